// Round 11
// baseline (14310.686 us; speedup 1.0000x reference)
//
#include <hip/hip_runtime.h>
#include <stdint.h>

namespace {

constexpr int H = 512, V = 64, B = 8, T = 48, D1 = 49, NDEC = 45, NSTEP = 102;
constexpr int NBLK = 256, TPB = 512;          // EXACTLY 256 blocks: co-residency
constexpr int NG = 8, GMEM = NBLK / NG;       // 32 per barrier group

// ws element offsets (4-byte units)
constexpr size_t OFF_PUB = 0;                       // [par][j<512][b<8][p<8]
constexpr size_t OFF_IDX = 2 * 32768;               // NSTEP*8 ints
constexpr size_t OFF_BAR = OFF_IDX + NSTEP * B;     // 512 ints (flags at +256)
constexpr size_t OFF_YP  = OFF_BAR + 512;           // yp[p<8][b<8][o<64] floats
constexpr size_t OFF_XW  = OFF_YP + 8 * 8 * 64;     // xw[t<48][b<8][j<512]

// relaxed agent-scope (sc1) accessors: L3-coherent, no fences, no L2 flush
__device__ __forceinline__ float ldA(const float* p) {
  return __hip_atomic_load(p, __ATOMIC_RELAXED, __HIP_MEMORY_SCOPE_AGENT);
}
__device__ __forceinline__ void stA(float* p, float v) {
  __hip_atomic_store(p, v, __ATOMIC_RELAXED, __HIP_MEMORY_SCOPE_AGENT);
}
__device__ __forceinline__ int ldAi(const int* p) {
  return __hip_atomic_load(p, __ATOMIC_RELAXED, __HIP_MEMORY_SCOPE_AGENT);
}
__device__ __forceinline__ void stAi(int* p, int v) {
  __hip_atomic_store(p, v, __ATOMIC_RELAXED, __HIP_MEMORY_SCOPE_AGENT);
}

__device__ __forceinline__ void tf2x32(uint32_t k0, uint32_t k1,
                                       uint32_t& x0, uint32_t& x1) {
  const uint32_t ks2 = k0 ^ k1 ^ 0x1BD11BDAu;
  x0 += k0; x1 += k1;
#define RR(r) { x0 += x1; x1 = (x1 << (r)) | (x1 >> (32-(r))); x1 ^= x0; }
  RR(13) RR(15) RR(26) RR(6)  x0 += k1;  x1 += ks2 + 1u;
  RR(17) RR(29) RR(16) RR(24) x0 += ks2; x1 += k0 + 2u;
  RR(13) RR(15) RR(26) RR(6)  x0 += k0;  x1 += k1 + 3u;
  RR(17) RR(29) RR(16) RR(24) x0 += k1;  x1 += ks2 + 4u;
  RR(13) RR(15) RR(26) RR(6)  x0 += ks2; x1 += k0 + 5u;
#undef RR
}

__device__ __forceinline__ float gumbel_from_bits(uint32_t bits) {
  float u = __uint_as_float((bits >> 9) | 0x3F800000u) - 1.0f;
  u = u + 1e-9f;
  return -logf(-logf(u));
}

// credit*lat, op-order identical to the r3-verified chain
__device__ __forceinline__ float qcalc(float tv, float lv, float dd) {
  const float inv = 1.0f / 24.0f, inv2 = inv * inv;
  float tc = fminf(fmaxf(tv, 1.0f), 48.0f);
  return fmaxf(0.0f, inv - fabsf((dd - tc) * inv2)) * lv;
}

__global__ __launch_bounds__(512) void k_zero(float* __restrict__ ws) {
  int* bar = (int*)ws + OFF_BAR;
  if (threadIdx.x < 512) stAi(&bar[threadIdx.x], 0);
  for (int i = threadIdx.x; i < 32768; i += 512) stA(&ws[i], 0.0f);  // pub par0
}

// fence-free two-level grid barrier (r6-r9 proven)
__device__ __forceinline__ void gbar(int* bar, int grp, int ep) {
  asm volatile("s_waitcnt vmcnt(0)" ::: "memory");
  __syncthreads();
  if (threadIdx.x == 0) {
    int old = __hip_atomic_fetch_add(&bar[16 + 16 * grp], 1,
                                     __ATOMIC_RELAXED, __HIP_MEMORY_SCOPE_AGENT);
    if (((old + 1) % GMEM) == 0) {
      int oldG = __hip_atomic_fetch_add(&bar[0], 1,
                                        __ATOMIC_RELAXED, __HIP_MEMORY_SCOPE_AGENT);
      if (((oldG + 1) & (NG - 1)) == 0) {
        #pragma unroll
        for (int q = 0; q < NG; ++q) stAi(&bar[160 + 16 * q], ep);
      }
    }
    int guard = 0;
    while (ldAi(&bar[160 + 16 * grp]) < ep) {
      __builtin_amdgcn_s_sleep(2);
      if (++guard > (1 << 20)) break;   // fail-visible, never hangs
    }
  }
  __syncthreads();
}

__global__ __launch_bounds__(TPB, 2)   // min 2 waves/EU -> 256-VGPR budget
void k_main(
    const float* __restrict__ x,  const float* __restrict__ wa,
    const float* __restrict__ ba, const float* __restrict__ lat,
    const float* __restrict__ tau,const float* __restrict__ we,
    const float* __restrict__ be, float* __restrict__ ws,
    float* __restrict__ out) {
  const int blk = blockIdx.x, tid = threadIdx.x;
  const int grp = blk % NG;
  float* pub = ws + OFF_PUB;
  float* yp  = ws + OFF_YP;
  float* xw  = ws + OFF_XW;
  int* idxA = (int*)ws + OFF_IDX;
  int* bar  = (int*)ws + OFF_BAR;

  const int p  = blk >> 5;          // 0..7 (64-i chunk)
  const int g  = blk & 31;          // 0..31 (16-ho group)
  const int w  = tid >> 6, lane = tid & 63;
  const int cb = p * 64;            // chunk base in i/j space
  const bool isG0  = (g == 0);      // partial-y producer for this p
  const bool isFin = (g == 31);     // y finisher for sample fb = p
  const int fb = p;

  __shared__ float s_pub[64 * 65 + 8];  // staged chunk partials, stride-65 pad
  __shared__ float s_h[8 * 64];         // h[b][il]
  __shared__ float s_hd2[8 * 64];       // g0: h_del[b][il] for partial y
  __shared__ float s_buf[8 * 16 * 49];  // delay partials [b*16+hl][49] (24.5KB)
  __shared__ int   s_ptr[8], s_cidx[8], s_done8[8];

  // STEP-INVARIANT q = credit*lat in VGPRs (wave w owns rows 2w, 2w+1)
  float4 qA[16], qB[16];

  // ---------------- init ----------------
  for (int q2 = tid; q2 < 8 * 16 * 49; q2 += TPB) s_buf[q2] = 0.0f;
  if (tid < 8) { s_ptr[tid] = 0; s_cidx[tid] = 0; s_done8[tid] = 0; }
  {
    const int hoA = g * 16 + w * 2;
    const float dd = (float)lane;
    const float* tauA = tau + (size_t)hoA * H + cb;
    const float* latA = lat + (size_t)hoA * H + cb;
    const float* tauB = tauA + H;
    const float* latB = latA + H;
    #pragma unroll
    for (int c = 0; c < 16; ++c) {
      float4 ta = *(const float4*)(tauA + c * 4);
      float4 la = *(const float4*)(latA + c * 4);
      float4 tb = *(const float4*)(tauB + c * 4);
      float4 lb = *(const float4*)(latB + c * 4);
      float4 ra, rb;
      ra.x = qcalc(ta.x, la.x, dd); ra.y = qcalc(ta.y, la.y, dd);
      ra.z = qcalc(ta.z, la.z, dd); ra.w = qcalc(ta.w, la.w, dd);
      rb.x = qcalc(tb.x, lb.x, dd); rb.y = qcalc(tb.y, lb.y, dd);
      rb.z = qcalc(tb.z, lb.z, dd); rb.w = qcalc(tb.w, lb.w, dd);
      qA[c] = ra; qB[c] = rb;
    }
  }
  // precompute xw[t][b][j] for this p-chunk (g<24 covers t=2g,2g+1)
  if (g < 24) {
    #pragma unroll
    for (int tt = 0; tt < 2; ++tt) {
      int t0 = g * 2 + tt;
      int b = (tid >> 6) & 7, il = tid & 63;
      int j = cb + il;
      const float* xr = x + ((size_t)b * T + t0) * V;
      const float* war = wa + (size_t)j * V;
      float acc = 0.0f;
      #pragma unroll
      for (int v = 0; v < V; v += 4) {
        float4 w4 = *(const float4*)(war + v);
        float4 x4 = *(const float4*)(xr + v);
        acc = fmaf(w4.x, x4.x, acc); acc = fmaf(w4.y, x4.y, acc);
        acc = fmaf(w4.z, x4.z, acc); acc = fmaf(w4.w, x4.w, acc);
      }
      stA(&xw[((size_t)t0 * 8 + b) * 512 + j], acc);
    }
  }
  uint32_t ka = 0u, kb = (uint32_t)fb;
  tf2x32(0u, 42u, ka, kb);     // sample key for finisher (partitionable split)

  gbar(bar, grp, 1);

  // ---------------- 102 sequential steps ----------------
  for (int t = 0; t < NSTEP; ++t) {
    const bool thinkM = (t >= T && t < T + 9);
    const bool decM   = (t >= T + 9);

    // 1. replicated control-state update (thread b handles sample b)
    if (tid < 8 && t >= 1) {
      const int b = tid;
      const bool prevThink = (t - 1 >= T) && (t - 1 < T + 9);
      const bool aP = prevThink ? (s_done8[b] == 0) : true;
      if (t - 1 >= T) {
        int ix = ldAi(&idxA[(t - 1) * 8 + b]);
        if (aP) s_cidx[b] = ix;
        if (prevThink && (ix == 63 || (t - 1 - T) == 8)) s_done8[b] = 1;
      }
      if (aP) { int pv = s_ptr[b]; s_ptr[b] = (pv + 1 == D1) ? 0 : pv + 1; }
    }
    __syncthreads();

    int actM = 0;
    #pragma unroll
    for (int b = 0; b < B; ++b)
      actM |= ((thinkM ? (s_done8[b] ^ 1) : 1) & 1) << b;

    // 2. stage pub chunk (coalesced): 4096 floats = [il][b*8+p2]
    {
      const float* pubR = pub + ((size_t)(t & 1) * 32768 + (size_t)cb * 64);
      #pragma unroll
      for (int k = 0; k < 8; ++k) {
        int f = k * 512 + tid;
        float v = ldA(&pubR[f]);
        s_pub[(f >> 6) * 65 + (f & 63)] = v;
      }
    }
    __syncthreads();

    // 3. h for this block's chunk (1 per thread); g0 also records h_del
    {
      int il = tid & 63, b = tid >> 6;
      int j = cb + il;
      int sp = il * 65 + b * 8;
      float hd = ((s_pub[sp]   + s_pub[sp+1]) + (s_pub[sp+2] + s_pub[sp+3]))
               + ((s_pub[sp+4] + s_pub[sp+5]) + (s_pub[sp+6] + s_pub[sp+7]));
      if (isG0 && t >= T) s_hd2[b * 64 + il] = hd;
      float acc;
      if (t <= T) {     // encoder rows; first think step uses x[:,T-1,:]
        int xrow = (t < T) ? t : (T - 1);
        acc = (ba[j] + hd) + ldA(&xw[((size_t)xrow * 8 + b) * 512 + j]);
      } else {          // cur is exactly one-hot -> single add (bit-equal)
        acc = (ba[j] + hd) + wa[(size_t)j * V + s_cidx[b]];
      }
      s_h[b * 64 + il] = tanhf(acc);
    }
    __syncthreads();

    // 4. scatter: wave w owns rows (2w, 2w+1), lane = delay d; q in regs
    {
      float accA[8], accB[8];
      #pragma unroll
      for (int b = 0; b < B; ++b) { accA[b] = 0.0f; accB[b] = 0.0f; }
      #pragma unroll
      for (int ii = 0; ii < 64; ii += 4) {
        const float4 qa = qA[ii >> 2];
        const float4 qb = qB[ii >> 2];
        #pragma unroll
        for (int b = 0; b < B; ++b) {
          float4 h4 = *(const float4*)(&s_h[b * 64 + ii]);
          accA[b] = fmaf(qa.x, h4.x, accA[b]);
          accA[b] = fmaf(qa.y, h4.y, accA[b]);
          accA[b] = fmaf(qa.z, h4.z, accA[b]);
          accA[b] = fmaf(qa.w, h4.w, accA[b]);
          accB[b] = fmaf(qb.x, h4.x, accB[b]);
          accB[b] = fmaf(qb.y, h4.y, accB[b]);
          accB[b] = fmaf(qb.z, h4.z, accB[b]);
          accB[b] = fmaf(qb.w, h4.w, accB[b]);
        }
      }
      if (lane >= 1 && lane <= 48) {
        #pragma unroll
        for (int b = 0; b < B; ++b) {
          if ((actM >> b) & 1) {
            int slot = s_ptr[b] + lane; if (slot >= D1) slot -= D1;
            // d=48 is the FIRST write to the freshly-consumed slot:
            // overwrite implements the reference's slot-clear (deferred).
            int aA = (b * 16 + w * 2) * 49 + slot;
            float oA = s_buf[aA];
            s_buf[aA] = (lane == 48) ? accA[b] : (oA + accA[b]);
            int aB = (b * 16 + w * 2 + 1) * 49 + slot;
            float oB = s_buf[aB];
            s_buf[aB] = (lane == 48) ? accB[b] : (oB + accB[b]);
          }
        }
      }
    }
    __syncthreads();

    // 5. publish next step's h_del partials (ptr_{t+1} known NOW)
    if (tid < 128) {
      int hl = tid >> 3, b = tid & 7;
      int sn = ((actM >> b) & 1) ? s_ptr[b] + 1 : s_ptr[b];
      if (sn >= D1) sn -= D1;
      float val = s_buf[(b * 16 + hl) * 49 + sn];
      stA(&pub[(size_t)((t + 1) & 1) * 32768
               + (size_t)(g * 16 + hl) * 64 + b * 8 + p], val);
    }

    // 6. g0: partial y over this p-chunk -> yp[p][b][o], then flag
    if (isG0 && t >= T) {
      int b = tid >> 6, o = tid & 63;
      const float* wer = we + (size_t)o * H + cb;   // 16KB slice, L1-resident
      const float* hp  = &s_hd2[b * 64];
      float a2 = 0.0f;
      #pragma unroll
      for (int i2 = 0; i2 < 64; i2 += 4) {
        float4 w4 = *(const float4*)(wer + i2);
        a2 = fmaf(w4.x, hp[i2],     a2); a2 = fmaf(w4.y, hp[i2 + 1], a2);
        a2 = fmaf(w4.z, hp[i2 + 2], a2); a2 = fmaf(w4.w, hp[i2 + 3], a2);
      }
      stA(&yp[(size_t)p * 512 + b * 64 + o], a2);
      asm volatile("s_waitcnt vmcnt(0)" ::: "memory");
      __syncthreads();
      if (tid == 0) stAi(&bar[256 + 16 * p], t + 1);
    }

    // 7. finisher (p=fb, g=31): spin flags, sum partials, y/gumbel/idx
    if (isFin && t >= T) {
      if (tid < 64) {
        const int o = tid, it = t - T;
        if (o < 8) {
          int guard = 0;
          while (ldAi(&bar[256 + 16 * o]) < t + 1) {
            __builtin_amdgcn_s_sleep(1);
            if (++guard > (1 << 22)) break;   // fail-visible
          }
        }
        asm volatile("" ::: "memory");   // no hoisting loads above the spin
        const float* ypr = yp + fb * 64 + o;
        float y0 = ldA(ypr),        y1 = ldA(ypr + 512);
        float y2 = ldA(ypr + 1024), y3 = ldA(ypr + 1536);
        float y4 = ldA(ypr + 2048), y5 = ldA(ypr + 2560);
        float y6 = ldA(ypr + 3072), y7 = ldA(ypr + 3584);
        float y = (((y0 + y1) + (y2 + y3)) + ((y4 + y5) + (y6 + y7))) + be[o];
        if (decM && o < V - 1)
          out[((size_t)fb * NDEC + (t - T - 9)) * (V - 1) + o] = y;
        uint32_t data = (it < 9) ? (uint32_t)it : (uint32_t)(10000 + (it - 9));
        uint32_t e = 0u, f = data; tf2x32(ka, kb, e, f);
        uint32_t r0 = 0u, r1 = (uint32_t)o; tf2x32(e, f, r0, r1);
        float bv = y + gumbel_from_bits(r0 ^ r1);
        int bi = o;
        #pragma unroll
        for (int m = 32; m >= 1; m >>= 1) {
          float ov = __shfl_xor(bv, m, 64);
          int   oi = __shfl_xor(bi, m, 64);
          if (ov > bv || (ov == bv && oi < bi)) { bv = ov; bi = oi; }
        }
        if (o == 0) stAi(&idxA[t * 8 + fb], bi);
      }
    }

    gbar(bar, grp, t + 2);
  }
}

} // anonymous namespace

extern "C" void kernel_launch(void* const* d_in, const int* in_sizes, int n_in,
                              void* d_out, int out_size, void* d_ws, size_t ws_size,
                              hipStream_t stream) {
  (void)in_sizes; (void)n_in; (void)out_size; (void)ws_size;
  const float* x   = (const float*)d_in[0];
  const float* wa  = (const float*)d_in[1];
  const float* ba  = (const float*)d_in[2];
  const float* lat = (const float*)d_in[3];
  const float* tau = (const float*)d_in[4];
  const float* we  = (const float*)d_in[5];
  const float* be  = (const float*)d_in[6];
  float* out = (float*)d_out;
  float* ws  = (float*)d_ws;

  k_zero<<<dim3(1), dim3(512), 0, stream>>>(ws);
  k_main<<<dim3(NBLK), dim3(TPB), 0, stream>>>(x, wa, ba, lat, tau, we, be, ws, out);
}

// Round 12
// 13694.424 us; speedup vs baseline: 1.0450x; 1.0450x over previous
//
#include <hip/hip_runtime.h>
#include <stdint.h>

namespace {

constexpr int H = 512, V = 64, B = 8, T = 48, D1 = 49, NDEC = 45, NSTEP = 102;
constexpr int NBLK = 256, TPB = 512;          // EXACTLY 256 blocks: co-residency
constexpr int NG = 8, GMEM = NBLK / NG;       // 32 per barrier group

// ws element offsets (4-byte units)
constexpr size_t OFF_PUB = 0;                       // [par][j<512][b<8][p<8]
constexpr size_t OFF_IDX = 2 * 32768;               // NSTEP*8 ints
constexpr size_t OFF_BAR = OFF_IDX + NSTEP * B;     // 512 ints (flags at +256)
constexpr size_t OFF_YP  = OFF_BAR + 512;           // yp[p<8][b<8][o<64] floats
constexpr size_t OFF_XW  = OFF_YP + 8 * 8 * 64;     // xw[t<48][b<8][j<512]

// relaxed agent-scope (sc1) accessors: L3-coherent, no fences, no L2 flush
__device__ __forceinline__ float ldA(const float* p) {
  return __hip_atomic_load(p, __ATOMIC_RELAXED, __HIP_MEMORY_SCOPE_AGENT);
}
__device__ __forceinline__ void stA(float* p, float v) {
  __hip_atomic_store(p, v, __ATOMIC_RELAXED, __HIP_MEMORY_SCOPE_AGENT);
}
__device__ __forceinline__ int ldAi(const int* p) {
  return __hip_atomic_load(p, __ATOMIC_RELAXED, __HIP_MEMORY_SCOPE_AGENT);
}
__device__ __forceinline__ void stAi(int* p, int v) {
  __hip_atomic_store(p, v, __ATOMIC_RELAXED, __HIP_MEMORY_SCOPE_AGENT);
}

__device__ __forceinline__ void tf2x32(uint32_t k0, uint32_t k1,
                                       uint32_t& x0, uint32_t& x1) {
  const uint32_t ks2 = k0 ^ k1 ^ 0x1BD11BDAu;
  x0 += k0; x1 += k1;
#define RR(r) { x0 += x1; x1 = (x1 << (r)) | (x1 >> (32-(r))); x1 ^= x0; }
  RR(13) RR(15) RR(26) RR(6)  x0 += k1;  x1 += ks2 + 1u;
  RR(17) RR(29) RR(16) RR(24) x0 += ks2; x1 += k0 + 2u;
  RR(13) RR(15) RR(26) RR(6)  x0 += k0;  x1 += k1 + 3u;
  RR(17) RR(29) RR(16) RR(24) x0 += k1;  x1 += ks2 + 4u;
  RR(13) RR(15) RR(26) RR(6)  x0 += ks2; x1 += k0 + 5u;
#undef RR
}

__device__ __forceinline__ float gumbel_from_bits(uint32_t bits) {
  float u = __uint_as_float((bits >> 9) | 0x3F800000u) - 1.0f;
  u = u + 1e-9f;
  return -logf(-logf(u));
}

// credit*lat, op-order identical to the r3-verified chain
__device__ __forceinline__ float qcalc(float tv, float lv, float dd) {
  const float inv = 1.0f / 24.0f, inv2 = inv * inv;
  float tc = fminf(fmaxf(tv, 1.0f), 48.0f);
  return fmaxf(0.0f, inv - fabsf((dd - tc) * inv2)) * lv;
}

__global__ __launch_bounds__(512) void k_zero(float* __restrict__ ws) {
  int* bar = (int*)ws + OFF_BAR;
  if (threadIdx.x < 512) stAi(&bar[threadIdx.x], 0);
  for (int i = threadIdx.x; i < 32768; i += 512) stA(&ws[i], 0.0f);  // pub par0
}

// fence-free two-level grid barrier (r6-r11 proven)
__device__ __forceinline__ void gbar(int* bar, int grp, int ep) {
  asm volatile("s_waitcnt vmcnt(0)" ::: "memory");
  __syncthreads();
  if (threadIdx.x == 0) {
    int old = __hip_atomic_fetch_add(&bar[16 + 16 * grp], 1,
                                     __ATOMIC_RELAXED, __HIP_MEMORY_SCOPE_AGENT);
    if (((old + 1) % GMEM) == 0) {
      int oldG = __hip_atomic_fetch_add(&bar[0], 1,
                                        __ATOMIC_RELAXED, __HIP_MEMORY_SCOPE_AGENT);
      if (((oldG + 1) & (NG - 1)) == 0) {
        #pragma unroll
        for (int q = 0; q < NG; ++q) stAi(&bar[160 + 16 * q], ep);
      }
    }
    int guard = 0;
    while (ldAi(&bar[160 + 16 * grp]) < ep) {
      __builtin_amdgcn_s_sleep(2);
      if (++guard > (1 << 20)) break;   // fail-visible, never hangs
    }
  }
  __syncthreads();
}

__global__ __launch_bounds__(TPB)
__attribute__((amdgpu_waves_per_eu(2, 2)))   // pin 2 waves/EU -> 256-VGPR budget
void k_main(
    const float* __restrict__ x,  const float* __restrict__ wa,
    const float* __restrict__ ba, const float* __restrict__ lat,
    const float* __restrict__ tau,const float* __restrict__ we,
    const float* __restrict__ be, float* __restrict__ ws,
    float* __restrict__ out) {
  const int blk = blockIdx.x, tid = threadIdx.x;
  const int grp = blk % NG;
  float* pub = ws + OFF_PUB;
  float* yp  = ws + OFF_YP;
  float* xw  = ws + OFF_XW;
  int* idxA = (int*)ws + OFF_IDX;
  int* bar  = (int*)ws + OFF_BAR;

  const int p  = blk >> 5;          // 0..7 (64-i chunk)
  const int g  = blk & 31;          // 0..31 (16-ho group)
  const int w  = tid >> 6, lane = tid & 63;
  const int cb = p * 64;            // chunk base in i/j space
  const bool isG0  = (g == 0);      // partial-y producer for this p
  const bool isFin = (g == 31);     // y finisher for sample fb = p
  const int fb = p;

  __shared__ float s_h[8 * 64];         // h[b][il]
  __shared__ float s_hd2[8 * 64];       // g0: h_del[b][il] for partial y
  __shared__ float s_buf[8 * 16 * 49];  // delay partials [b*16+hl][49] (24.5KB)
  __shared__ int   s_ptr[8], s_cidx[8], s_done8[8];

  // STEP-INVARIANT q = credit*lat in NAMED float4 registers (no arrays ->
  // no alloca -> cannot be demoted to scratch without explicit spill).
  float4 qA0, qA1, qA2, qA3, qA4, qA5, qA6, qA7,
         qA8, qA9, qA10, qA11, qA12, qA13, qA14, qA15;
  float4 qB0, qB1, qB2, qB3, qB4, qB5, qB6, qB7,
         qB8, qB9, qB10, qB11, qB12, qB13, qB14, qB15;

  // ---------------- init ----------------
  for (int q2 = tid; q2 < 8 * 16 * 49; q2 += TPB) s_buf[q2] = 0.0f;
  if (tid < 8) { s_ptr[tid] = 0; s_cidx[tid] = 0; s_done8[tid] = 0; }
  {
    const int hoA = g * 16 + w * 2;
    const float dd = (float)lane;
    const float* tauA = tau + (size_t)hoA * H + cb;
    const float* latA = lat + (size_t)hoA * H + cb;
    const float* tauB = tauA + H;
    const float* latB = latA + H;
#define QINIT(c) { \
    float4 ta = *(const float4*)(tauA + (c) * 4); \
    float4 la = *(const float4*)(latA + (c) * 4); \
    float4 tb = *(const float4*)(tauB + (c) * 4); \
    float4 lb = *(const float4*)(latB + (c) * 4); \
    qA##c.x = qcalc(ta.x, la.x, dd); qA##c.y = qcalc(ta.y, la.y, dd); \
    qA##c.z = qcalc(ta.z, la.z, dd); qA##c.w = qcalc(ta.w, la.w, dd); \
    qB##c.x = qcalc(tb.x, lb.x, dd); qB##c.y = qcalc(tb.y, lb.y, dd); \
    qB##c.z = qcalc(tb.z, lb.z, dd); qB##c.w = qcalc(tb.w, lb.w, dd); }
    QINIT(0)  QINIT(1)  QINIT(2)  QINIT(3)
    QINIT(4)  QINIT(5)  QINIT(6)  QINIT(7)
    QINIT(8)  QINIT(9)  QINIT(10) QINIT(11)
    QINIT(12) QINIT(13) QINIT(14) QINIT(15)
#undef QINIT
  }
  // precompute xw[t][b][j] for this p-chunk (g<24 covers t=2g,2g+1)
  if (g < 24) {
    #pragma unroll
    for (int tt = 0; tt < 2; ++tt) {
      int t0 = g * 2 + tt;
      int b = (tid >> 6) & 7, il = tid & 63;
      int j = cb + il;
      const float* xr = x + ((size_t)b * T + t0) * V;
      const float* war = wa + (size_t)j * V;
      float acc = 0.0f;
      #pragma unroll
      for (int v = 0; v < V; v += 4) {
        float4 w4 = *(const float4*)(war + v);
        float4 x4 = *(const float4*)(xr + v);
        acc = fmaf(w4.x, x4.x, acc); acc = fmaf(w4.y, x4.y, acc);
        acc = fmaf(w4.z, x4.z, acc); acc = fmaf(w4.w, x4.w, acc);
      }
      stA(&xw[((size_t)t0 * 8 + b) * 512 + j], acc);
    }
  }
  uint32_t ka = 0u, kb = (uint32_t)fb;
  tf2x32(0u, 42u, ka, kb);     // sample key for finisher (partitionable split)

  gbar(bar, grp, 1);

  // ---------------- 102 sequential steps ----------------
  for (int t = 0; t < NSTEP; ++t) {
    const bool thinkM = (t >= T && t < T + 9);
    const bool decM   = (t >= T + 9);

    // 1. replicated control-state update (thread b handles sample b)
    if (tid < 8 && t >= 1) {
      const int b = tid;
      const bool prevThink = (t - 1 >= T) && (t - 1 < T + 9);
      const bool aP = prevThink ? (s_done8[b] == 0) : true;
      if (t - 1 >= T) {
        int ix = ldAi(&idxA[(t - 1) * 8 + b]);
        if (aP) s_cidx[b] = ix;
        if (prevThink && (ix == 63 || (t - 1 - T) == 8)) s_done8[b] = 1;
      }
      if (aP) { int pv = s_ptr[b]; s_ptr[b] = (pv + 1 == D1) ? 0 : pv + 1; }
    }
    __syncthreads();

    int actM = 0;
    #pragma unroll
    for (int b = 0; b < B; ++b)
      actM |= ((thinkM ? (s_done8[b] ^ 1) : 1) & 1) << b;

    // 2. h for this block's chunk — pub partials loaded DIRECTLY (fused
    //    stage: 8 sc1 loads from one 128B line per thread; no LDS roundtrip)
    {
      int il = tid & 63, b = tid >> 6;
      int j = cb + il;
      const float* pr = pub + ((size_t)(t & 1) * 32768 + (size_t)j * 64 + b * 8);
      float p0 = ldA(pr),     p1 = ldA(pr + 1), p2 = ldA(pr + 2), p3 = ldA(pr + 3);
      float p4 = ldA(pr + 4), p5 = ldA(pr + 5), p6 = ldA(pr + 6), p7 = ldA(pr + 7);
      float hd = ((p0 + p1) + (p2 + p3)) + ((p4 + p5) + (p6 + p7));
      if (isG0 && t >= T) s_hd2[b * 64 + il] = hd;
      float acc;
      if (t <= T) {     // encoder rows; first think step uses x[:,T-1,:]
        int xrow = (t < T) ? t : (T - 1);
        acc = (ba[j] + hd) + ldA(&xw[((size_t)xrow * 8 + b) * 512 + j]);
      } else {          // cur is exactly one-hot -> single add (bit-equal)
        acc = (ba[j] + hd) + wa[(size_t)j * V + s_cidx[b]];
      }
      s_h[b * 64 + il] = tanhf(acc);
    }
    __syncthreads();

    // 3. scatter: wave w owns rows (2w, 2w+1), lane = delay d; q in regs
    {
      float accA[8], accB[8];
      #pragma unroll
      for (int b = 0; b < B; ++b) { accA[b] = 0.0f; accB[b] = 0.0f; }
#define SCAT4(c) { \
      const float4 qa = qA##c; const float4 qb = qB##c; \
      _Pragma("unroll") \
      for (int b = 0; b < B; ++b) { \
        float4 h4 = *(const float4*)(&s_h[b * 64 + (c) * 4]); \
        accA[b] = fmaf(qa.x, h4.x, accA[b]); \
        accA[b] = fmaf(qa.y, h4.y, accA[b]); \
        accA[b] = fmaf(qa.z, h4.z, accA[b]); \
        accA[b] = fmaf(qa.w, h4.w, accA[b]); \
        accB[b] = fmaf(qb.x, h4.x, accB[b]); \
        accB[b] = fmaf(qb.y, h4.y, accB[b]); \
        accB[b] = fmaf(qb.z, h4.z, accB[b]); \
        accB[b] = fmaf(qb.w, h4.w, accB[b]); \
      } }
      SCAT4(0)  SCAT4(1)  SCAT4(2)  SCAT4(3)
      SCAT4(4)  SCAT4(5)  SCAT4(6)  SCAT4(7)
      SCAT4(8)  SCAT4(9)  SCAT4(10) SCAT4(11)
      SCAT4(12) SCAT4(13) SCAT4(14) SCAT4(15)
#undef SCAT4
      if (lane >= 1 && lane <= 48) {
        #pragma unroll
        for (int b = 0; b < B; ++b) {
          if ((actM >> b) & 1) {
            int slot = s_ptr[b] + lane; if (slot >= D1) slot -= D1;
            // d=48 is the FIRST write to the freshly-consumed slot:
            // overwrite implements the reference's slot-clear (deferred).
            int aA = (b * 16 + w * 2) * 49 + slot;
            float oA = s_buf[aA];
            s_buf[aA] = (lane == 48) ? accA[b] : (oA + accA[b]);
            int aB = (b * 16 + w * 2 + 1) * 49 + slot;
            float oB = s_buf[aB];
            s_buf[aB] = (lane == 48) ? accB[b] : (oB + accB[b]);
          }
        }
      }
    }
    __syncthreads();

    // 4. publish next step's h_del partials (ptr_{t+1} known NOW)
    if (tid < 128) {
      int hl = tid >> 3, b = tid & 7;
      int sn = ((actM >> b) & 1) ? s_ptr[b] + 1 : s_ptr[b];
      if (sn >= D1) sn -= D1;
      float val = s_buf[(b * 16 + hl) * 49 + sn];
      stA(&pub[(size_t)((t + 1) & 1) * 32768
               + (size_t)(g * 16 + hl) * 64 + b * 8 + p], val);
    }

    // 5. g0: partial y over this p-chunk -> yp[p][b][o], then flag
    if (isG0 && t >= T) {
      int b = tid >> 6, o = tid & 63;
      const float* wer = we + (size_t)o * H + cb;   // 16KB slice, L1-resident
      const float* hp  = &s_hd2[b * 64];
      float a2 = 0.0f;
      #pragma unroll
      for (int i2 = 0; i2 < 64; i2 += 4) {
        float4 w4 = *(const float4*)(wer + i2);
        a2 = fmaf(w4.x, hp[i2],     a2); a2 = fmaf(w4.y, hp[i2 + 1], a2);
        a2 = fmaf(w4.z, hp[i2 + 2], a2); a2 = fmaf(w4.w, hp[i2 + 3], a2);
      }
      stA(&yp[(size_t)p * 512 + b * 64 + o], a2);
      asm volatile("s_waitcnt vmcnt(0)" ::: "memory");
      __syncthreads();
      if (tid == 0) stAi(&bar[256 + 16 * p], t + 1);
    }

    // 6. finisher (p=fb, g=31): spin flags, sum partials, y/gumbel/idx
    if (isFin && t >= T) {
      if (tid < 64) {
        const int o = tid, it = t - T;
        if (o < 8) {
          int guard = 0;
          while (ldAi(&bar[256 + 16 * o]) < t + 1) {
            __builtin_amdgcn_s_sleep(1);
            if (++guard > (1 << 22)) break;   // fail-visible
          }
        }
        asm volatile("" ::: "memory");   // no hoisting loads above the spin
        const float* ypr = yp + fb * 64 + o;
        float y0 = ldA(ypr),        y1 = ldA(ypr + 512);
        float y2 = ldA(ypr + 1024), y3 = ldA(ypr + 1536);
        float y4 = ldA(ypr + 2048), y5 = ldA(ypr + 2560);
        float y6 = ldA(ypr + 3072), y7 = ldA(ypr + 3584);
        float y = (((y0 + y1) + (y2 + y3)) + ((y4 + y5) + (y6 + y7))) + be[o];
        if (decM && o < V - 1)
          out[((size_t)fb * NDEC + (t - T - 9)) * (V - 1) + o] = y;
        uint32_t data = (it < 9) ? (uint32_t)it : (uint32_t)(10000 + (it - 9));
        uint32_t e = 0u, f = data; tf2x32(ka, kb, e, f);
        uint32_t r0 = 0u, r1 = (uint32_t)o; tf2x32(e, f, r0, r1);
        float bv = y + gumbel_from_bits(r0 ^ r1);
        int bi = o;
        #pragma unroll
        for (int m = 32; m >= 1; m >>= 1) {
          float ov = __shfl_xor(bv, m, 64);
          int   oi = __shfl_xor(bi, m, 64);
          if (ov > bv || (ov == bv && oi < bi)) { bv = ov; bi = oi; }
        }
        if (o == 0) stAi(&idxA[t * 8 + fb], bi);
      }
    }

    gbar(bar, grp, t + 2);
  }
}

} // anonymous namespace

extern "C" void kernel_launch(void* const* d_in, const int* in_sizes, int n_in,
                              void* d_out, int out_size, void* d_ws, size_t ws_size,
                              hipStream_t stream) {
  (void)in_sizes; (void)n_in; (void)out_size; (void)ws_size;
  const float* x   = (const float*)d_in[0];
  const float* wa  = (const float*)d_in[1];
  const float* ba  = (const float*)d_in[2];
  const float* lat = (const float*)d_in[3];
  const float* tau = (const float*)d_in[4];
  const float* we  = (const float*)d_in[5];
  const float* be  = (const float*)d_in[6];
  float* out = (float*)d_out;
  float* ws  = (float*)d_ws;

  k_zero<<<dim3(1), dim3(512), 0, stream>>>(ws);
  k_main<<<dim3(NBLK), dim3(TPB), 0, stream>>>(x, wa, ba, lat, tau, we, be, ws, out);
}

// Round 13
// 1724.769 us; speedup vs baseline: 8.2972x; 7.9399x over previous
//
#include <hip/hip_runtime.h>
#include <stdint.h>

namespace {

constexpr int H = 512, V = 64, B = 8, T = 48, D1 = 49, NDEC = 45, NSTEP = 102;
constexpr int NBLK = 256, TPB = 512;          // EXACTLY 256 blocks: co-residency
constexpr int NG = 8, GMEM = NBLK / NG;       // 32 per barrier group

// ws element offsets (4-byte units)
constexpr size_t OFF_PUB = 0;                       // [par][j<512][b<8][p<8]
constexpr size_t OFF_IDX = 2 * 32768;               // NSTEP*8 ints
constexpr size_t OFF_BAR = OFF_IDX + NSTEP * B;     // 512 ints (flags at +256)
constexpr size_t OFF_YP  = OFF_BAR + 512;           // yp[p<8][b<8][o<64] floats
constexpr size_t OFF_XW  = OFF_YP + 8 * 8 * 64;     // xw[t<48][b<8][j<512]

// relaxed agent-scope (sc1) accessors: L3-coherent, no fences, no L2 flush
__device__ __forceinline__ float ldA(const float* p) {
  return __hip_atomic_load(p, __ATOMIC_RELAXED, __HIP_MEMORY_SCOPE_AGENT);
}
__device__ __forceinline__ void stA(float* p, float v) {
  __hip_atomic_store(p, v, __ATOMIC_RELAXED, __HIP_MEMORY_SCOPE_AGENT);
}
__device__ __forceinline__ int ldAi(const int* p) {
  return __hip_atomic_load(p, __ATOMIC_RELAXED, __HIP_MEMORY_SCOPE_AGENT);
}
__device__ __forceinline__ void stAi(int* p, int v) {
  __hip_atomic_store(p, v, __ATOMIC_RELAXED, __HIP_MEMORY_SCOPE_AGENT);
}

__device__ __forceinline__ void tf2x32(uint32_t k0, uint32_t k1,
                                       uint32_t& x0, uint32_t& x1) {
  const uint32_t ks2 = k0 ^ k1 ^ 0x1BD11BDAu;
  x0 += k0; x1 += k1;
#define RR(r) { x0 += x1; x1 = (x1 << (r)) | (x1 >> (32-(r))); x1 ^= x0; }
  RR(13) RR(15) RR(26) RR(6)  x0 += k1;  x1 += ks2 + 1u;
  RR(17) RR(29) RR(16) RR(24) x0 += ks2; x1 += k0 + 2u;
  RR(13) RR(15) RR(26) RR(6)  x0 += k0;  x1 += k1 + 3u;
  RR(17) RR(29) RR(16) RR(24) x0 += k1;  x1 += ks2 + 4u;
  RR(13) RR(15) RR(26) RR(6)  x0 += ks2; x1 += k0 + 5u;
#undef RR
}

__device__ __forceinline__ float gumbel_from_bits(uint32_t bits) {
  float u = __uint_as_float((bits >> 9) | 0x3F800000u) - 1.0f;
  u = u + 1e-9f;
  return -logf(-logf(u));
}

__global__ __launch_bounds__(512) void k_zero(float* __restrict__ ws) {
  int* bar = (int*)ws + OFF_BAR;
  if (threadIdx.x < 512) stAi(&bar[threadIdx.x], 0);
  for (int i = threadIdx.x; i < 32768; i += 512) stA(&ws[i], 0.0f);  // pub par0
}

// fence-free two-level grid barrier (r6-r12 proven)
__device__ __forceinline__ void gbar(int* bar, int grp, int ep) {
  asm volatile("s_waitcnt vmcnt(0)" ::: "memory");
  __syncthreads();
  if (threadIdx.x == 0) {
    int old = __hip_atomic_fetch_add(&bar[16 + 16 * grp], 1,
                                     __ATOMIC_RELAXED, __HIP_MEMORY_SCOPE_AGENT);
    if (((old + 1) & (GMEM - 1)) == 0) {
      int oldG = __hip_atomic_fetch_add(&bar[0], 1,
                                        __ATOMIC_RELAXED, __HIP_MEMORY_SCOPE_AGENT);
      if (((oldG + 1) & (NG - 1)) == 0) {
        #pragma unroll
        for (int q = 0; q < NG; ++q) stAi(&bar[160 + 16 * q], ep);
      }
    }
    int guard = 0;
    while (ldAi(&bar[160 + 16 * grp]) < ep) {
      __builtin_amdgcn_s_sleep(2);
      if (++guard > (1 << 20)) break;   // fail-visible, never hangs
    }
  }
  __syncthreads();
}

__global__ __launch_bounds__(TPB, 4)   // r9-proven: VGPR ~64, no spill
void k_main(
    const float* __restrict__ x,  const float* __restrict__ wa,
    const float* __restrict__ ba, const float* __restrict__ lat,
    const float* __restrict__ tau,const float* __restrict__ we,
    const float* __restrict__ be, float* __restrict__ ws,
    float* __restrict__ out) {
  const int blk = blockIdx.x, tid = threadIdx.x;
  const int grp = blk % NG;
  float* pub = ws + OFF_PUB;
  float* yp  = ws + OFF_YP;
  float* xw  = ws + OFF_XW;
  int* idxA = (int*)ws + OFF_IDX;
  int* bar  = (int*)ws + OFF_BAR;

  const int p  = blk >> 5;          // 0..7 (64-i chunk)
  const int g  = blk & 31;          // 0..31 (16-ho group)
  const int w  = tid >> 6, lane = tid & 63;
  const int cb = p * 64;            // chunk base in i/j space
  const bool isG0  = (g == 0);      // partial-y producer for this p
  const bool isFin = (g == 31);     // y finisher for sample fb = p
  const int fb = p;

  __shared__ float s_h[8 * 64];         // h[b][il]
  __shared__ float s_hd2[8 * 64];       // g0: h_del[b][il] for partial y
  __shared__ float s_tc[16 * 64];       // pre-clipped tau for 16 ho x 64 i
  __shared__ float s_lat[16 * 64];
  __shared__ float s_buf[8 * 16 * 49];  // delay partials [b*16+hl][49] (24.5KB)
  __shared__ int   s_ptr[8], s_cidx[8], s_done8[8];

  // ---------------- init ----------------
  for (int q2 = tid; q2 < 8 * 16 * 49; q2 += TPB) s_buf[q2] = 0.0f;
  for (int q2 = tid; q2 < 16 * 64; q2 += TPB) {
    int hl = q2 >> 6, ii = q2 & 63;
    int ho = g * 16 + hl, i = cb + ii;
    float tv = tau[(size_t)ho * H + i];
    s_tc[q2]  = fminf(fmaxf(tv, 1.0f), 48.0f);   // r3-verified clip ops
    s_lat[q2] = lat[(size_t)ho * H + i];
  }
  if (tid < 8) { s_ptr[tid] = 0; s_cidx[tid] = 0; s_done8[tid] = 0; }
  // precompute xw[t][b][j] for this p-chunk (g<24 covers t=2g,2g+1)
  if (g < 24) {
    #pragma unroll
    for (int tt = 0; tt < 2; ++tt) {
      int t0 = g * 2 + tt;
      int b = (tid >> 6) & 7, il = tid & 63;
      int j = cb + il;
      const float* xr = x + ((size_t)b * T + t0) * V;
      const float* war = wa + (size_t)j * V;
      float acc = 0.0f;
      #pragma unroll
      for (int v = 0; v < V; v += 4) {
        float4 w4 = *(const float4*)(war + v);
        float4 x4 = *(const float4*)(xr + v);
        acc = fmaf(w4.x, x4.x, acc); acc = fmaf(w4.y, x4.y, acc);
        acc = fmaf(w4.z, x4.z, acc); acc = fmaf(w4.w, x4.w, acc);
      }
      stA(&xw[((size_t)t0 * 8 + b) * 512 + j], acc);
    }
  }
  uint32_t ka = 0u, kb = (uint32_t)fb;
  tf2x32(0u, 42u, ka, kb);     // sample key for finisher (partitionable split)

  gbar(bar, grp, 1);

  // ---------------- 102 sequential steps ----------------
  for (int t = 0; t < NSTEP; ++t) {
    const bool thinkM = (t >= T && t < T + 9);
    const bool decM   = (t >= T + 9);

    // 1. replicated control-state update (thread b handles sample b)
    if (tid < 8 && t >= 1) {
      const int b = tid;
      const bool prevThink = (t - 1 >= T) && (t - 1 < T + 9);
      const bool aP = prevThink ? (s_done8[b] == 0) : true;
      if (t - 1 >= T) {
        int ix = ldAi(&idxA[(t - 1) * 8 + b]);
        if (aP) s_cidx[b] = ix;
        if (prevThink && (ix == 63 || (t - 1 - T) == 8)) s_done8[b] = 1;
      }
      if (aP) { int pv = s_ptr[b]; s_ptr[b] = (pv + 1 == D1) ? 0 : pv + 1; }
    }
    __syncthreads();

    int actM = 0;
    #pragma unroll
    for (int b = 0; b < B; ++b)
      actM |= ((thinkM ? (s_done8[b] ^ 1) : 1) & 1) << b;

    // 2. h for this block's chunk — pub partials loaded DIRECTLY (fused
    //    stage: 8 sc1 loads from one 32B run per thread; no LDS roundtrip)
    {
      int il = tid & 63, b = tid >> 6;
      int j = cb + il;
      const float* pr = pub + ((size_t)(t & 1) * 32768 + (size_t)j * 64 + b * 8);
      float p0 = ldA(pr),     p1 = ldA(pr + 1), p2 = ldA(pr + 2), p3 = ldA(pr + 3);
      float p4 = ldA(pr + 4), p5 = ldA(pr + 5), p6 = ldA(pr + 6), p7 = ldA(pr + 7);
      float hd = ((p0 + p1) + (p2 + p3)) + ((p4 + p5) + (p6 + p7));
      if (isG0 && t >= T) s_hd2[b * 64 + il] = hd;
      float acc;
      if (t <= T) {     // encoder rows; first think step uses x[:,T-1,:]
        int xrow = (t < T) ? t : (T - 1);
        acc = (ba[j] + hd) + ldA(&xw[((size_t)xrow * 8 + b) * 512 + j]);
      } else {          // cur is exactly one-hot -> single add (bit-equal)
        acc = (ba[j] + hd) + wa[(size_t)j * V + s_cidx[b]];
      }
      s_h[b * 64 + il] = tanhf(acc);
    }
    __syncthreads();

    // 3. scatter: wave w owns rows (2w, 2w+1), lane = delay d (r9-proven)
    {
      const float dd = (float)lane;
      const float inv = 1.0f / 24.0f, inv2 = inv * inv;
      float accA[8], accB[8];
      #pragma unroll
      for (int b = 0; b < B; ++b) { accA[b] = 0.0f; accB[b] = 0.0f; }
      const float* tcA = &s_tc[(w * 2) * 64];
      const float* ltA = &s_lat[(w * 2) * 64];
      const float* tcB = &s_tc[(w * 2 + 1) * 64];
      const float* ltB = &s_lat[(w * 2 + 1) * 64];
      #pragma unroll 4
      for (int ii = 0; ii < 64; ii += 4) {
        float4 tA = *(const float4*)(tcA + ii);
        float4 lA = *(const float4*)(ltA + ii);
        float4 tB = *(const float4*)(tcB + ii);
        float4 lB = *(const float4*)(ltB + ii);
        float qA[4], qB[4];
        #pragma unroll
        for (int k = 0; k < 4; ++k) {
          // per-(ho,i) op sequence identical to r3: sub,mul,abs,rsub,max,mul
          float ta = ((const float*)&tA)[k];
          qA[k] = fmaxf(0.0f, inv - fabsf((dd - ta) * inv2)) * ((const float*)&lA)[k];
          float tb = ((const float*)&tB)[k];
          qB[k] = fmaxf(0.0f, inv - fabsf((dd - tb) * inv2)) * ((const float*)&lB)[k];
        }
        #pragma unroll
        for (int b = 0; b < B; ++b) {
          float4 h4 = *(const float4*)(&s_h[b * 64 + ii]);
          const float* hp = (const float*)&h4;
          #pragma unroll
          for (int k = 0; k < 4; ++k) accA[b] = fmaf(qA[k], hp[k], accA[b]);
          #pragma unroll
          for (int k = 0; k < 4; ++k) accB[b] = fmaf(qB[k], hp[k], accB[b]);
        }
      }
      if (lane >= 1 && lane <= 48) {
        #pragma unroll
        for (int b = 0; b < B; ++b) {
          if ((actM >> b) & 1) {
            int slot = s_ptr[b] + lane; if (slot >= D1) slot -= D1;
            // d=48 is the FIRST write to the freshly-consumed slot:
            // overwrite implements the reference's slot-clear (deferred).
            int aA = (b * 16 + w * 2) * 49 + slot;
            float oA = s_buf[aA];
            s_buf[aA] = (lane == 48) ? accA[b] : (oA + accA[b]);
            int aB = (b * 16 + w * 2 + 1) * 49 + slot;
            float oB = s_buf[aB];
            s_buf[aB] = (lane == 48) ? accB[b] : (oB + accB[b]);
          }
        }
      }
    }
    __syncthreads();

    // 4. publish next step's h_del partials (ptr_{t+1} known NOW)
    if (tid < 128) {
      int hl = tid >> 3, b = tid & 7;
      int sn = ((actM >> b) & 1) ? s_ptr[b] + 1 : s_ptr[b];
      if (sn >= D1) sn -= D1;
      float val = s_buf[(b * 16 + hl) * 49 + sn];
      stA(&pub[(size_t)((t + 1) & 1) * 32768
               + (size_t)(g * 16 + hl) * 64 + b * 8 + p], val);
    }

    // 5. g0: partial y over this p-chunk -> yp[p][b][o], then flag
    if (isG0 && t >= T) {
      int b = tid >> 6, o = tid & 63;
      const float* wer = we + (size_t)o * H + cb;   // 16KB slice, L1-resident
      const float* hp  = &s_hd2[b * 64];
      float a2 = 0.0f;
      #pragma unroll
      for (int i2 = 0; i2 < 64; i2 += 4) {
        float4 w4 = *(const float4*)(wer + i2);
        a2 = fmaf(w4.x, hp[i2],     a2); a2 = fmaf(w4.y, hp[i2 + 1], a2);
        a2 = fmaf(w4.z, hp[i2 + 2], a2); a2 = fmaf(w4.w, hp[i2 + 3], a2);
      }
      stA(&yp[(size_t)p * 512 + b * 64 + o], a2);
      asm volatile("s_waitcnt vmcnt(0)" ::: "memory");
      __syncthreads();
      if (tid == 0) stAi(&bar[256 + 16 * p], t + 1);
    }

    // 6. finisher (p=fb, g=31): spin flags, sum partials, y/gumbel/idx
    if (isFin && t >= T) {
      if (tid < 64) {
        const int o = tid, it = t - T;
        if (o < 8) {
          int guard = 0;
          while (ldAi(&bar[256 + 16 * o]) < t + 1) {
            __builtin_amdgcn_s_sleep(1);
            if (++guard > (1 << 22)) break;   // fail-visible
          }
        }
        asm volatile("" ::: "memory");   // no hoisting loads above the spin
        const float* ypr = yp + fb * 64 + o;
        float y0 = ldA(ypr),        y1 = ldA(ypr + 512);
        float y2 = ldA(ypr + 1024), y3 = ldA(ypr + 1536);
        float y4 = ldA(ypr + 2048), y5 = ldA(ypr + 2560);
        float y6 = ldA(ypr + 3072), y7 = ldA(ypr + 3584);
        float y = (((y0 + y1) + (y2 + y3)) + ((y4 + y5) + (y6 + y7))) + be[o];
        if (decM && o < V - 1)
          out[((size_t)fb * NDEC + (t - T - 9)) * (V - 1) + o] = y;
        uint32_t data = (it < 9) ? (uint32_t)it : (uint32_t)(10000 + (it - 9));
        uint32_t e = 0u, f = data; tf2x32(ka, kb, e, f);
        uint32_t r0 = 0u, r1 = (uint32_t)o; tf2x32(e, f, r0, r1);
        float bv = y + gumbel_from_bits(r0 ^ r1);
        int bi = o;
        #pragma unroll
        for (int m = 32; m >= 1; m >>= 1) {
          float ov = __shfl_xor(bv, m, 64);
          int   oi = __shfl_xor(bi, m, 64);
          if (ov > bv || (ov == bv && oi < bi)) { bv = ov; bi = oi; }
        }
        if (o == 0) stAi(&idxA[t * 8 + fb], bi);
      }
    }

    gbar(bar, grp, t + 2);
  }
}

} // anonymous namespace

extern "C" void kernel_launch(void* const* d_in, const int* in_sizes, int n_in,
                              void* d_out, int out_size, void* d_ws, size_t ws_size,
                              hipStream_t stream) {
  (void)in_sizes; (void)n_in; (void)out_size; (void)ws_size;
  const float* x   = (const float*)d_in[0];
  const float* wa  = (const float*)d_in[1];
  const float* ba  = (const float*)d_in[2];
  const float* lat = (const float*)d_in[3];
  const float* tau = (const float*)d_in[4];
  const float* we  = (const float*)d_in[5];
  const float* be  = (const float*)d_in[6];
  float* out = (float*)d_out;
  float* ws  = (float*)d_ws;

  k_zero<<<dim3(1), dim3(512), 0, stream>>>(ws);
  k_main<<<dim3(NBLK), dim3(TPB), 0, stream>>>(x, wa, ba, lat, tau, we, be, ws, out);
}

// Round 14
// 1596.423 us; speedup vs baseline: 8.9642x; 1.0804x over previous
//
#include <hip/hip_runtime.h>
#include <stdint.h>

namespace {

constexpr int H = 512, V = 64, B = 8, T = 48, D1 = 49, NDEC = 45, NSTEP = 102;
constexpr int NBLK = 256, TPB = 512;          // exactly 256 blocks, co-resident
constexpr int NG = 8, GMEM = NBLK / NG;       // init barrier groups

// ws element offsets (4-byte units)
constexpr size_t OFF_PUB  = 0;                  // 4 parities x [j<512][b<8][p<8]
constexpr size_t OFF_IDX  = 131072;             // NSTEP*8 ints
constexpr size_t OFF_PFLG = 132096;             // 256 ints [g<32][p<8] (128B-aligned)
constexpr size_t OFF_YPF  = 132352;             // 8 ints (ypflag per p)
constexpr size_t OFF_YF   = 132416;             // 8 ints (yflag per sample)
constexpr size_t OFF_BAR  = 132544;             // 512 ints (init gbar only)
constexpr size_t OFF_YP   = 133056;             // 4 parities x yp[p<8][b<8][o<64]
constexpr size_t OFF_XW   = 149440;             // xw[t<48][b<8][j<512]

// relaxed agent-scope (sc1) accessors: L3-coherent, no fences, no L2 flush
__device__ __forceinline__ float ldA(const float* p) {
  return __hip_atomic_load(p, __ATOMIC_RELAXED, __HIP_MEMORY_SCOPE_AGENT);
}
__device__ __forceinline__ void stA(float* p, float v) {
  __hip_atomic_store(p, v, __ATOMIC_RELAXED, __HIP_MEMORY_SCOPE_AGENT);
}
__device__ __forceinline__ int ldAi(const int* p) {
  return __hip_atomic_load(p, __ATOMIC_RELAXED, __HIP_MEMORY_SCOPE_AGENT);
}
__device__ __forceinline__ void stAi(int* p, int v) {
  __hip_atomic_store(p, v, __ATOMIC_RELAXED, __HIP_MEMORY_SCOPE_AGENT);
}

__device__ __forceinline__ void tf2x32(uint32_t k0, uint32_t k1,
                                       uint32_t& x0, uint32_t& x1) {
  const uint32_t ks2 = k0 ^ k1 ^ 0x1BD11BDAu;
  x0 += k0; x1 += k1;
#define RR(r) { x0 += x1; x1 = (x1 << (r)) | (x1 >> (32-(r))); x1 ^= x0; }
  RR(13) RR(15) RR(26) RR(6)  x0 += k1;  x1 += ks2 + 1u;
  RR(17) RR(29) RR(16) RR(24) x0 += ks2; x1 += k0 + 2u;
  RR(13) RR(15) RR(26) RR(6)  x0 += k0;  x1 += k1 + 3u;
  RR(17) RR(29) RR(16) RR(24) x0 += k1;  x1 += ks2 + 4u;
  RR(13) RR(15) RR(26) RR(6)  x0 += ks2; x1 += k0 + 5u;
#undef RR
}

__device__ __forceinline__ float gumbel_from_bits(uint32_t bits) {
  float u = __uint_as_float((bits >> 9) | 0x3F800000u) - 1.0f;
  u = u + 1e-9f;
  return -logf(-logf(u));
}

__global__ __launch_bounds__(512) void k_zero(float* __restrict__ ws) {
  int* ib = (int*)ws;
  // zero pflag/ypf/yf/bar region [OFF_PFLG, OFF_BAR+512)
  for (size_t i = OFF_PFLG + threadIdx.x; i < OFF_BAR + 512; i += 512)
    stAi(&ib[i], 0);
  for (int i = threadIdx.x; i < 32768; i += 512) stA(&ws[i], 0.0f);  // pub par0
}

// two-level grid barrier — used ONCE after init (r6-r13 proven)
__device__ __forceinline__ void gbar(int* bar, int grp, int ep) {
  asm volatile("s_waitcnt vmcnt(0)" ::: "memory");
  __syncthreads();
  if (threadIdx.x == 0) {
    int old = __hip_atomic_fetch_add(&bar[16 + 16 * grp], 1,
                                     __ATOMIC_RELAXED, __HIP_MEMORY_SCOPE_AGENT);
    if (((old + 1) & (GMEM - 1)) == 0) {
      int oldG = __hip_atomic_fetch_add(&bar[0], 1,
                                        __ATOMIC_RELAXED, __HIP_MEMORY_SCOPE_AGENT);
      if (((oldG + 1) & (NG - 1)) == 0) {
        #pragma unroll
        for (int q = 0; q < NG; ++q) stAi(&bar[160 + 16 * q], ep);
      }
    }
    int guard = 0;
    while (ldAi(&bar[160 + 16 * grp]) < ep) {
      __builtin_amdgcn_s_sleep(2);
      if (++guard > (1 << 20)) break;
    }
  }
  __syncthreads();
}

__global__ __launch_bounds__(TPB, 4)   // r13-proven: VGPR 64, no spill
void k_main(
    const float* __restrict__ x,  const float* __restrict__ wa,
    const float* __restrict__ ba, const float* __restrict__ lat,
    const float* __restrict__ tau,const float* __restrict__ we,
    const float* __restrict__ be, float* __restrict__ ws,
    float* __restrict__ out) {
  const int blk = blockIdx.x, tid = threadIdx.x;
  float* pub = ws + OFF_PUB;
  float* yp  = ws + OFF_YP;
  float* xw  = ws + OFF_XW;
  int* idxA  = (int*)ws + OFF_IDX;
  int* pflag = (int*)ws + OFF_PFLG;
  int* ypf   = (int*)ws + OFF_YPF;
  int* yf    = (int*)ws + OFF_YF;
  int* bar   = (int*)ws + OFF_BAR;

  const int p  = blk >> 5;          // 0..7 (64-i chunk)
  const int g  = blk & 31;          // 0..31 (16-ho group)
  const int w  = tid >> 6, lane = tid & 63;
  const int cb = p * 64;            // chunk base in i/j space
  const bool isG0  = (g == 0);      // partial-y producer for this p
  const bool isFin = (g == 31);     // y finisher for sample fb = p
  const int fb = p;

  __shared__ float s_h[8 * 64];         // h[b][il]
  __shared__ float s_hd2[8 * 64];       // g0: h_del[b][il] for partial y
  __shared__ float s_tc[16 * 64];       // pre-clipped tau for 16 ho x 64 i
  __shared__ float s_lat[16 * 64];
  __shared__ float s_buf[8 * 16 * 49];  // delay partials [b*16+hl][49]
  __shared__ int   s_ptr[8], s_cidx[8], s_done8[8];

  // ---------------- init ----------------
  for (int q2 = tid; q2 < 8 * 16 * 49; q2 += TPB) s_buf[q2] = 0.0f;
  for (int q2 = tid; q2 < 16 * 64; q2 += TPB) {
    int hl = q2 >> 6, ii = q2 & 63;
    int ho = g * 16 + hl, i = cb + ii;
    float tv = tau[(size_t)ho * H + i];
    s_tc[q2]  = fminf(fmaxf(tv, 1.0f), 48.0f);   // r3-verified clip ops
    s_lat[q2] = lat[(size_t)ho * H + i];
  }
  if (tid < 8) { s_ptr[tid] = 0; s_cidx[tid] = 0; s_done8[tid] = 0; }
  if (g < 24) {   // xw[t][b][j] precompute (g<24 covers t=2g,2g+1)
    #pragma unroll
    for (int tt = 0; tt < 2; ++tt) {
      int t0 = g * 2 + tt;
      int b = (tid >> 6) & 7, il = tid & 63;
      int j = cb + il;
      const float* xr = x + ((size_t)b * T + t0) * V;
      const float* war = wa + (size_t)j * V;
      float acc = 0.0f;
      #pragma unroll
      for (int v = 0; v < V; v += 4) {
        float4 w4 = *(const float4*)(war + v);
        float4 x4 = *(const float4*)(xr + v);
        acc = fmaf(w4.x, x4.x, acc); acc = fmaf(w4.y, x4.y, acc);
        acc = fmaf(w4.z, x4.z, acc); acc = fmaf(w4.w, x4.w, acc);
      }
      stA(&xw[((size_t)t0 * 8 + b) * 512 + j], acc);
    }
  }
  uint32_t ka = 0u, kb = (uint32_t)fb;
  tf2x32(0u, 42u, ka, kb);     // sample key (partitionable split)

  gbar(bar, blk % NG, 1);      // ONE global barrier: init visibility

  // ---------------- 102 sequential steps, flag-synced ----------------
  for (int t = 0; t < NSTEP; ++t) {
    const bool thinkM = (t >= T && t < T + 9);
    const bool decM   = (t >= T + 9);
    const int needY   = (t - 1 >= T) ? 1 : 0;

    // A. spin: 32 producer pflags >= t (lanes 0-31), yflags >= t-1 (32-39)
    if (tid < 64) {
      int guard = 0;
      while (true) {
        int pred = 1;
        if (lane < 32)      pred = (ldAi(&pflag[p * 32 + lane]) >= t);
        else if (lane < 40 && needY) pred = (ldAi(&yf[lane - 32]) >= t - 1);
        if (__all(pred)) break;
        __builtin_amdgcn_s_sleep(1);
        if (++guard > (1 << 22)) break;   // fail-visible, never hangs
      }
    }
    __syncthreads();
    asm volatile("" ::: "memory");

    // B. replicated control-state update (thread b handles sample b)
    if (tid < 8 && t >= 1) {
      const int b = tid;
      const bool prevThink = (t - 1 >= T) && (t - 1 < T + 9);
      const bool aP = prevThink ? (s_done8[b] == 0) : true;
      if (t - 1 >= T) {
        int ix = ldAi(&idxA[(t - 1) * 8 + b]);
        if (aP) s_cidx[b] = ix;
        if (prevThink && (ix == 63 || (t - 1 - T) == 8)) s_done8[b] = 1;
      }
      if (aP) { int pv = s_ptr[b]; s_ptr[b] = (pv + 1 == D1) ? 0 : pv + 1; }
    }
    __syncthreads();

    int actM = 0;
    #pragma unroll
    for (int b = 0; b < B; ++b)
      actM |= ((thinkM ? (s_done8[b] ^ 1) : 1) & 1) << b;

    // C. h for this block's chunk (fused pub loads, parity t%4)
    {
      int il = tid & 63, b = tid >> 6;
      int j = cb + il;
      const float* pr = pub + ((size_t)(t & 3) * 32768 + (size_t)j * 64 + b * 8);
      float p0 = ldA(pr),     p1 = ldA(pr + 1), p2 = ldA(pr + 2), p3 = ldA(pr + 3);
      float p4 = ldA(pr + 4), p5 = ldA(pr + 5), p6 = ldA(pr + 6), p7 = ldA(pr + 7);
      float hd = ((p0 + p1) + (p2 + p3)) + ((p4 + p5) + (p6 + p7));
      if (isG0 && t >= T) s_hd2[b * 64 + il] = hd;
      float acc;
      if (t <= T) {     // encoder rows; first think step uses x[:,T-1,:]
        int xrow = (t < T) ? t : (T - 1);
        acc = (ba[j] + hd) + ldA(&xw[((size_t)xrow * 8 + b) * 512 + j]);
      } else {          // cur is exactly one-hot -> single add (bit-equal)
        acc = (ba[j] + hd) + wa[(size_t)j * V + s_cidx[b]];
      }
      s_h[b * 64 + il] = tanhf(acc);
    }
    __syncthreads();

    // D. g0: partial y EARLY (hides under everyone else's scatter)
    if (isG0 && t >= T) {
      int b = tid >> 6, o = tid & 63;
      const float* wer = we + (size_t)o * H + cb;
      const float* hp  = &s_hd2[b * 64];
      float a2 = 0.0f;
      #pragma unroll
      for (int i2 = 0; i2 < 64; i2 += 4) {
        float4 w4 = *(const float4*)(wer + i2);
        a2 = fmaf(w4.x, hp[i2],     a2); a2 = fmaf(w4.y, hp[i2 + 1], a2);
        a2 = fmaf(w4.z, hp[i2 + 2], a2); a2 = fmaf(w4.w, hp[i2 + 3], a2);
      }
      stA(&yp[(size_t)(t & 3) * 4096 + (size_t)p * 512 + b * 64 + o], a2);
      asm volatile("s_waitcnt vmcnt(0)" ::: "memory");
      __syncthreads();
      if (tid == 0) stAi(&ypf[p], t);
    }

    // E. scatter: wave w owns rows (2w, 2w+1), lane = delay d (r9-proven)
    {
      const float dd = (float)lane;
      const float inv = 1.0f / 24.0f, inv2 = inv * inv;
      float accA[8], accB[8];
      #pragma unroll
      for (int b = 0; b < B; ++b) { accA[b] = 0.0f; accB[b] = 0.0f; }
      const float* tcA = &s_tc[(w * 2) * 64];
      const float* ltA = &s_lat[(w * 2) * 64];
      const float* tcB = &s_tc[(w * 2 + 1) * 64];
      const float* ltB = &s_lat[(w * 2 + 1) * 64];
      #pragma unroll 4
      for (int ii = 0; ii < 64; ii += 4) {
        float4 tA = *(const float4*)(tcA + ii);
        float4 lA = *(const float4*)(ltA + ii);
        float4 tB = *(const float4*)(tcB + ii);
        float4 lB = *(const float4*)(ltB + ii);
        float qA[4], qB[4];
        #pragma unroll
        for (int k = 0; k < 4; ++k) {
          float ta = ((const float*)&tA)[k];
          qA[k] = fmaxf(0.0f, inv - fabsf((dd - ta) * inv2)) * ((const float*)&lA)[k];
          float tb = ((const float*)&tB)[k];
          qB[k] = fmaxf(0.0f, inv - fabsf((dd - tb) * inv2)) * ((const float*)&lB)[k];
        }
        #pragma unroll
        for (int b = 0; b < B; ++b) {
          float4 h4 = *(const float4*)(&s_h[b * 64 + ii]);
          const float* hp = (const float*)&h4;
          #pragma unroll
          for (int k = 0; k < 4; ++k) accA[b] = fmaf(qA[k], hp[k], accA[b]);
          #pragma unroll
          for (int k = 0; k < 4; ++k) accB[b] = fmaf(qB[k], hp[k], accB[b]);
        }
      }
      if (lane >= 1 && lane <= 48) {
        #pragma unroll
        for (int b = 0; b < B; ++b) {
          if ((actM >> b) & 1) {
            int slot = s_ptr[b] + lane; if (slot >= D1) slot -= D1;
            // d=48 first-write implements the deferred slot-clear (r5+ proven)
            int aA = (b * 16 + w * 2) * 49 + slot;
            float oA = s_buf[aA];
            s_buf[aA] = (lane == 48) ? accA[b] : (oA + accA[b]);
            int aB = (b * 16 + w * 2 + 1) * 49 + slot;
            float oB = s_buf[aB];
            s_buf[aB] = (lane == 48) ? accB[b] : (oB + accB[b]);
          }
        }
      }
    }
    __syncthreads();

    // F. publish pub(t+1) partials (parity (t+1)%4), then pflag = t+1
    if (tid < 128) {
      int hl = tid >> 3, b = tid & 7;
      int sn = ((actM >> b) & 1) ? s_ptr[b] + 1 : s_ptr[b];
      if (sn >= D1) sn -= D1;
      float val = s_buf[(b * 16 + hl) * 49 + sn];
      stA(&pub[(size_t)((t + 1) & 3) * 32768
               + (size_t)(g * 16 + hl) * 64 + b * 8 + p], val);
    }
    asm volatile("s_waitcnt vmcnt(0)" ::: "memory");
    __syncthreads();
    if (tid == 0) stAi(&pflag[g * 8 + p], t + 1);

    // G. finisher: y for sample fb (after publish -> off critical path)
    if (isFin && t >= T && tid < 64) {
      const int o = tid, it = t - T;
      if (o < 8) {
        int guard = 0;
        while (ldAi(&ypf[o]) < t) {
          __builtin_amdgcn_s_sleep(1);
          if (++guard > (1 << 22)) break;   // fail-visible
        }
      }
      asm volatile("" ::: "memory");   // no hoisting loads above the spin
      const float* ypr = yp + (size_t)(t & 3) * 4096 + fb * 64 + o;
      float y0 = ldA(ypr),        y1 = ldA(ypr + 512);
      float y2 = ldA(ypr + 1024), y3 = ldA(ypr + 1536);
      float y4 = ldA(ypr + 2048), y5 = ldA(ypr + 2560);
      float y6 = ldA(ypr + 3072), y7 = ldA(ypr + 3584);
      float y = (((y0 + y1) + (y2 + y3)) + ((y4 + y5) + (y6 + y7))) + be[o];
      if (decM && o < V - 1)
        out[((size_t)fb * NDEC + (t - T - 9)) * (V - 1) + o] = y;
      uint32_t data = (it < 9) ? (uint32_t)it : (uint32_t)(10000 + (it - 9));
      uint32_t e = 0u, f = data; tf2x32(ka, kb, e, f);
      uint32_t r0 = 0u, r1 = (uint32_t)o; tf2x32(e, f, r0, r1);
      float bv = y + gumbel_from_bits(r0 ^ r1);
      int bi = o;
      #pragma unroll
      for (int m = 32; m >= 1; m >>= 1) {
        float ov = __shfl_xor(bv, m, 64);
        int   oi = __shfl_xor(bi, m, 64);
        if (ov > bv || (ov == bv && oi < bi)) { bv = ov; bi = oi; }
      }
      if (o == 0) {
        stAi(&idxA[t * 8 + fb], bi);
        asm volatile("s_waitcnt vmcnt(0)" ::: "memory");  // order idxA < yflag
        stAi(&yf[fb], t);
      }
    }
  }
}

} // anonymous namespace

extern "C" void kernel_launch(void* const* d_in, const int* in_sizes, int n_in,
                              void* d_out, int out_size, void* d_ws, size_t ws_size,
                              hipStream_t stream) {
  (void)in_sizes; (void)n_in; (void)out_size; (void)ws_size;
  const float* x   = (const float*)d_in[0];
  const float* wa  = (const float*)d_in[1];
  const float* ba  = (const float*)d_in[2];
  const float* lat = (const float*)d_in[3];
  const float* tau = (const float*)d_in[4];
  const float* we  = (const float*)d_in[5];
  const float* be  = (const float*)d_in[6];
  float* out = (float*)d_out;
  float* ws  = (float*)d_ws;

  k_zero<<<dim3(1), dim3(512), 0, stream>>>(ws);
  k_main<<<dim3(NBLK), dim3(TPB), 0, stream>>>(x, wa, ba, lat, tau, we, be, ws, out);
}